// Round 10
// baseline (216.065 us; speedup 1.0000x reference)
//
#include <hip/hip_runtime.h>
#include <hip/hip_bf16.h>

#define V_IN 128
#define U_IN 64
#define HID 128
#define K1  (V_IN + HID + U_IN)   // 320

typedef __attribute__((ext_vector_type(8))) short bf16x8;
typedef __attribute__((ext_vector_type(4))) float f32x4;

static __device__ __forceinline__ unsigned short f2bf(float f) {
    __hip_bfloat16 h = __float2bfloat16(f);
    union { __hip_bfloat16 h; unsigned short u; } v; v.h = h;
    return v.u;
}
static __device__ __forceinline__ unsigned int f2bf2(float lo, float hi) {
    __hip_bfloat162 h2 = __float22bfloat162_rn(make_float2(lo, hi));  // v_cvt_pk_bf16_f32
    union { __hip_bfloat162 h; unsigned int u; } v; v.h = h2;
    return v.u;
}

// ---------- fused: zero deg + W1/W2 -> bf16 transposed ----------
__global__ __launch_bounds__(256) void zero_prep(
    const float* __restrict__ W1, const float* __restrict__ W2,
    unsigned short* __restrict__ Wt1, unsigned short* __restrict__ Wt2,
    int* __restrict__ deg, int N)
{
    int id = blockIdx.x * 256 + threadIdx.x;
    if (id < N) deg[id] = 0;
    if (id < HID * K1) {                     // Wt1: [128][320]
        int c = id / K1, k = id - c * K1;
        Wt1[id] = f2bf(W1[(size_t)k * HID + c]);
    }
    if (id < HID * HID) {                    // Wt2: [128][128]
        int c = id >> 7, k = id & 127;
        Wt2[id] = f2bf(W2[(size_t)k * HID + c]);
    }
}

// ---------- CSR build ----------

__global__ __launch_bounds__(256) void hist_kernel(
    const int* __restrict__ col, int* __restrict__ deg, int E)
{
    int e = blockIdx.x * 256 + threadIdx.x;
    if (e < E) atomicAdd(&deg[col[e]], 1);
}

// partial sums: each block covers 1024 elements of deg
__global__ __launch_bounds__(256) void scan_partial(
    const int* __restrict__ deg, int* __restrict__ blockSums, int N)
{
    __shared__ int sdata[256];
    int base = blockIdx.x * 1024;
    int tid  = threadIdx.x;
    int s = 0;
    #pragma unroll
    for (int j = 0; j < 4; ++j) {
        int i = base + tid * 4 + j;
        if (i < N) s += deg[i];
    }
    sdata[tid] = s;
    __syncthreads();
    for (int off = 128; off > 0; off >>= 1) {
        if (tid < off) sdata[tid] += sdata[tid + off];
        __syncthreads();
    }
    if (tid == 0) blockSums[blockIdx.x] = sdata[0];
}

// final: computes its own blockSums prefix (scan_blocksums kernel folded in)
__global__ __launch_bounds__(256) void scan_final(
    const int* __restrict__ deg, const int* __restrict__ blockSums,
    int* __restrict__ offsets, int* __restrict__ cur, int N, int E)
{
    __shared__ int sdata[256];
    __shared__ int rdata[256];
    int tid = threadIdx.x;

    // prefix of blockSums[0..blockIdx-1] via strided reduce (NB <= 1024)
    int part = 0;
    for (int i = tid; i < (int)blockIdx.x; i += 256) part += blockSums[i];
    rdata[tid] = part;
    __syncthreads();
    for (int off = 128; off > 0; off >>= 1) {
        if (tid < off) rdata[tid] += rdata[tid + off];
        __syncthreads();
    }
    const int blockPrefix = rdata[0];

    int base = blockIdx.x * 1024;
    int loc[4];
    int s = 0;
    #pragma unroll
    for (int j = 0; j < 4; ++j) {
        int i = base + tid * 4 + j;
        loc[j] = (i < N) ? deg[i] : 0;
        s += loc[j];
    }
    int mine = s;
    sdata[tid] = s;
    __syncthreads();
    for (int off = 1; off < 256; off <<= 1) {
        int t = (tid >= off) ? sdata[tid - off] : 0;
        __syncthreads();
        sdata[tid] += t;
        __syncthreads();
    }
    int prefix = blockPrefix + sdata[tid] - mine;
    #pragma unroll
    for (int j = 0; j < 4; ++j) {
        int i = base + tid * 4 + j;
        if (i < N) { offsets[i] = prefix; cur[i] = prefix; prefix += loc[j]; }
    }
    if (blockIdx.x == 0 && tid == 0) offsets[N] = E;
}

__global__ __launch_bounds__(256) void fill_kernel(
    const int* __restrict__ col, int* __restrict__ cur,
    int* __restrict__ eidx, int E)
{
    int e = blockIdx.x * 256 + threadIdx.x;
    if (e < E) {
        int p = atomicAdd(&cur[col[e]], 1);
        eidx[p] = e;
    }
}

// ---------- fused gather + 2-layer MLP via bf16 MFMA ----------
// block = 512 threads = 8 waves; wave w owns output cols [16w, 16w+15];
// ROWS = 32 nodes/block, two 16-row tiles per wave share its in-reg W frags.
// Gather: eidx slice in LDS, ILP-8 edge walks, NT loads (read-once data).
#define ROWS 32
#define LDA_E 328
#define LDH_E 136
#define ECAP 1280

__global__ __launch_bounds__(512, 4) void mlp_mfma(
    const float* __restrict__ x,
    const float* __restrict__ edge_attr,
    const int*   __restrict__ offsets,
    const int*   __restrict__ eidx,
    const float* __restrict__ u,
    const int*   __restrict__ batch,
    const unsigned short* __restrict__ Wt1,
    const unsigned short* __restrict__ Wt2,
    const float* __restrict__ b1, const float* __restrict__ b2,
    float* __restrict__ out, int N)
{
    __shared__ __align__(16) unsigned short A[ROWS * LDA_E];
    __shared__ __align__(16) unsigned short H[ROWS * LDH_E];
    __shared__ int Eidx[ECAP];
    const int tid  = threadIdx.x;
    const int n0   = blockIdx.x * ROWS;
    const int lane = tid & 63;
    const int wave = tid >> 6;       // 0..7 = which 16-col slice
    const int l15  = lane & 15;
    const int lhi  = lane >> 4;      // 0..3
    const int wcol = wave * 16 + l15;

    // ---- stage this tile's eidx slice into LDS (coalesced, once)
    const int nEnd   = (n0 + ROWS < N) ? n0 + ROWS : N;
    const int s_base = offsets[n0];
    const int s_end  = offsets[nEnd];
    const int cnt    = (s_end - s_base < ECAP) ? s_end - s_base : ECAP;
    for (int i = tid; i < cnt; i += 512) Eidx[i] = eidx[s_base + i];

    // ---- stage x (32 float4 segs/row) and u (16 segs/row): 32*48 = 1536 tasks
    #pragma unroll
    for (int it = 0; it < 3; ++it) {
        int t   = tid + it * 512;
        int row = t / 48;
        int s   = t - row * 48;
        int n   = n0 + row;
        unsigned short* Arow = &A[row * LDA_E];
        f32x4 v = {0.f, 0.f, 0.f, 0.f};
        int colbase;
        if (s < 32) {                                // x: cols 0..127 (read-once -> NT)
            if (n < N) v = __builtin_nontemporal_load((const f32x4*)(x + (size_t)n * V_IN) + s);
            colbase = s * 4;
        } else {                                     // u: cols 256..319 (reused -> cached)
            if (n < N) {
                int b = batch[n];
                v = *((const f32x4*)(u + (size_t)b * U_IN) + (s - 32));
            }
            colbase = V_IN + HID + (s - 32) * 4;
        }
        uint2 o; o.x = f2bf2(v[0], v[1]); o.y = f2bf2(v[2], v[3]);
        *(uint2*)&Arow[colbase] = o;
    }
    __syncthreads();   // Eidx visible

    // ---- gather agg into A cols 128..255: 32 rows x 32 chunks, ILP-8,
    //      indices from LDS, rows via nontemporal loads
    #pragma unroll
    for (int it = 0; it < 2; ++it) {
        int t   = tid + it * 512;
        int row = t >> 5;
        int c   = t & 31;
        int n   = n0 + row;
        f32x4 a0 = {0.f, 0.f, 0.f, 0.f};
        f32x4 a1 = {0.f, 0.f, 0.f, 0.f};
        f32x4 a2 = {0.f, 0.f, 0.f, 0.f};
        f32x4 a3 = {0.f, 0.f, 0.f, 0.f};
        if (n < N) {
            int ls = offsets[n]     - s_base;
            int le = offsets[n + 1] - s_base;
            int j = ls;
            for (; j + 7 < le; j += 8) {             // 8 edges in flight
                int e0, e1, e2, e3, e4, e5, e6, e7;
                if (j + 7 < ECAP) {
                    e0 = Eidx[j];     e1 = Eidx[j + 1];
                    e2 = Eidx[j + 2]; e3 = Eidx[j + 3];
                    e4 = Eidx[j + 4]; e5 = Eidx[j + 5];
                    e6 = Eidx[j + 6]; e7 = Eidx[j + 7];
                } else {
                    e0 = eidx[s_base + j];     e1 = eidx[s_base + j + 1];
                    e2 = eidx[s_base + j + 2]; e3 = eidx[s_base + j + 3];
                    e4 = eidx[s_base + j + 4]; e5 = eidx[s_base + j + 5];
                    e6 = eidx[s_base + j + 6]; e7 = eidx[s_base + j + 7];
                }
                f32x4 v0 = __builtin_nontemporal_load((const f32x4*)(edge_attr + (size_t)e0 * HID) + c);
                f32x4 v1 = __builtin_nontemporal_load((const f32x4*)(edge_attr + (size_t)e1 * HID) + c);
                f32x4 v2 = __builtin_nontemporal_load((const f32x4*)(edge_attr + (size_t)e2 * HID) + c);
                f32x4 v3 = __builtin_nontemporal_load((const f32x4*)(edge_attr + (size_t)e3 * HID) + c);
                f32x4 v4 = __builtin_nontemporal_load((const f32x4*)(edge_attr + (size_t)e4 * HID) + c);
                f32x4 v5 = __builtin_nontemporal_load((const f32x4*)(edge_attr + (size_t)e5 * HID) + c);
                f32x4 v6 = __builtin_nontemporal_load((const f32x4*)(edge_attr + (size_t)e6 * HID) + c);
                f32x4 v7 = __builtin_nontemporal_load((const f32x4*)(edge_attr + (size_t)e7 * HID) + c);
                a0 += v0; a1 += v1; a2 += v2; a3 += v3;
                a0 += v4; a1 += v5; a2 += v6; a3 += v7;
            }
            if (j + 3 < le) {                        // one 4-wide round
                int e0, e1, e2, e3;
                if (j + 3 < ECAP) {
                    e0 = Eidx[j];     e1 = Eidx[j + 1];
                    e2 = Eidx[j + 2]; e3 = Eidx[j + 3];
                } else {
                    e0 = eidx[s_base + j];     e1 = eidx[s_base + j + 1];
                    e2 = eidx[s_base + j + 2]; e3 = eidx[s_base + j + 3];
                }
                f32x4 v0 = __builtin_nontemporal_load((const f32x4*)(edge_attr + (size_t)e0 * HID) + c);
                f32x4 v1 = __builtin_nontemporal_load((const f32x4*)(edge_attr + (size_t)e1 * HID) + c);
                f32x4 v2 = __builtin_nontemporal_load((const f32x4*)(edge_attr + (size_t)e2 * HID) + c);
                f32x4 v3 = __builtin_nontemporal_load((const f32x4*)(edge_attr + (size_t)e3 * HID) + c);
                a0 += v0; a1 += v1; a2 += v2; a3 += v3;
                j += 4;
            }
            for (; j < le; ++j) {
                int e0 = (j < ECAP) ? Eidx[j] : eidx[s_base + j];
                a0 += __builtin_nontemporal_load((const f32x4*)(edge_attr + (size_t)e0 * HID) + c);
            }
        }
        f32x4 asum = (a0 + a1) + (a2 + a3);
        uint2 o;
        o.x = f2bf2(asum[0], asum[1]);
        o.y = f2bf2(asum[2], asum[3]);
        *(uint2*)&A[row * LDA_E + V_IN + c * 4] = o;
    }

    // keep W-frag loads out of the gather's register window
    __builtin_amdgcn_sched_barrier(0);

    // ---- W fragments into registers (B-operand: col=l15, k contiguous)
    bf16x8 w1f[10], w2f[4];
    #pragma unroll
    for (int ks = 0; ks < 10; ++ks)
        w1f[ks] = *(const bf16x8*)(Wt1 + (size_t)wcol * K1 + ks * 32 + lhi * 8);
    #pragma unroll
    for (int ks = 0; ks < 4; ++ks)
        w2f[ks] = *(const bf16x8*)(Wt2 + (size_t)wcol * HID + ks * 32 + lhi * 8);
    const float b1v = b1[wcol];
    const float b2v = b2[wcol];

    __syncthreads();

    // ---- layer 1: two 16-row tiles share w1f
    f32x4 acc[2] = {{0.f, 0.f, 0.f, 0.f}, {0.f, 0.f, 0.f, 0.f}};
    #pragma unroll
    for (int ks = 0; ks < 10; ++ks) {
        #pragma unroll
        for (int h = 0; h < 2; ++h) {
            bf16x8 af = *(const bf16x8*)&A[(h * 16 + l15) * LDA_E + ks * 32 + lhi * 8];
            acc[h] = __builtin_amdgcn_mfma_f32_16x16x32_bf16(af, w1f[ks], acc[h], 0, 0, 0);
        }
    }
    // bias + relu -> H (D layout: row = lhi*4+r, col = l15 in wave's slice)
    #pragma unroll
    for (int h = 0; h < 2; ++h)
        #pragma unroll
        for (int r = 0; r < 4; ++r) {
            float hv = fmaxf(acc[h][r] + b1v, 0.f);
            H[(h * 16 + lhi * 4 + r) * LDH_E + wcol] = f2bf(hv);
        }
    __syncthreads();

    // ---- layer 2: two 16-row tiles share w2f
    f32x4 acc2[2] = {{0.f, 0.f, 0.f, 0.f}, {0.f, 0.f, 0.f, 0.f}};
    #pragma unroll
    for (int ks = 0; ks < 4; ++ks) {
        #pragma unroll
        for (int h = 0; h < 2; ++h) {
            bf16x8 hf = *(const bf16x8*)&H[(h * 16 + l15) * LDH_E + ks * 32 + lhi * 8];
            acc2[h] = __builtin_amdgcn_mfma_f32_16x16x32_bf16(hf, w2f[ks], acc2[h], 0, 0, 0);
        }
    }
    #pragma unroll
    for (int h = 0; h < 2; ++h)
        #pragma unroll
        for (int r = 0; r < 4; ++r) {
            int n = n0 + h * 16 + lhi * 4 + r;
            if (n < N)
                __builtin_nontemporal_store(acc2[h][r] + b2v, out + (size_t)n * HID + wcol);
        }
}

extern "C" void kernel_launch(void* const* d_in, const int* in_sizes, int n_in,
                              void* d_out, int out_size, void* d_ws, size_t ws_size,
                              hipStream_t stream) {
    const float* x          = (const float*)d_in[0];
    const int*   edge_index = (const int*)  d_in[1];
    const float* edge_attr  = (const float*)d_in[2];
    const float* u          = (const float*)d_in[3];
    const int*   batch      = (const int*)  d_in[4];
    const float* W1         = (const float*)d_in[5];
    const float* b1         = (const float*)d_in[6];
    const float* W2         = (const float*)d_in[7];
    const float* b2         = (const float*)d_in[8];
    float* out = (float*)d_out;

    const int N = in_sizes[0] / V_IN;
    const int E = in_sizes[1] / 2;
    const int* col = edge_index + E;   // row 1 = destination

    // ws layout
    unsigned short* Wt1  = (unsigned short*)d_ws;        // 320*128 bf16
    unsigned short* Wt2  = Wt1 + (size_t)K1 * HID;       // 128*128 bf16
    int* deg       = (int*)(Wt2 + (size_t)HID * HID);
    int* cur       = deg + N;
    int* offsets   = cur + N;
    int* blockSums = offsets + N + 1;
    int* eidx      = blockSums + 2048;

    const int NB = (N + 1023) / 1024;
    const int ZP = ((N > HID * K1 ? N : HID * K1) + 255) / 256;

    zero_prep   <<<ZP, 256, 0, stream>>>(W1, W2, Wt1, Wt2, deg, N);
    hist_kernel <<<(E + 255) / 256, 256, 0, stream>>>(col, deg, E);
    scan_partial<<<NB, 256, 0, stream>>>(deg, blockSums, N);
    scan_final  <<<NB, 256, 0, stream>>>(deg, blockSums, offsets, cur, N, E);
    fill_kernel <<<(E + 255) / 256, 256, 0, stream>>>(col, cur, eidx, E);

    mlp_mfma<<<(N + ROWS - 1) / ROWS, 512, 0, stream>>>(
        x, edge_attr, offsets, eidx, u, batch, Wt1, Wt2, b1, b2, out, N);
}

// Round 11
// 201.471 us; speedup vs baseline: 1.0724x; 1.0724x over previous
//
#include <hip/hip_runtime.h>
#include <hip/hip_bf16.h>

#define V_IN 128
#define U_IN 64
#define HID 128
#define K1  (V_IN + HID + U_IN)   // 320

typedef __attribute__((ext_vector_type(8))) short bf16x8;
typedef __attribute__((ext_vector_type(4))) float f32x4;

static __device__ __forceinline__ unsigned short f2bf(float f) {
    __hip_bfloat16 h = __float2bfloat16(f);
    union { __hip_bfloat16 h; unsigned short u; } v; v.h = h;
    return v.u;
}
static __device__ __forceinline__ unsigned int f2bf2(float lo, float hi) {
    __hip_bfloat162 h2 = __float22bfloat162_rn(make_float2(lo, hi));  // v_cvt_pk_bf16_f32
    union { __hip_bfloat162 h; unsigned int u; } v; v.h = h2;
    return v.u;
}

// ---------- fused: zero deg + W1/W2 -> bf16 transposed ----------
__global__ __launch_bounds__(256) void zero_prep(
    const float* __restrict__ W1, const float* __restrict__ W2,
    unsigned short* __restrict__ Wt1, unsigned short* __restrict__ Wt2,
    int* __restrict__ deg, int N)
{
    int id = blockIdx.x * 256 + threadIdx.x;
    if (id < N) deg[id] = 0;
    if (id < HID * K1) {                     // Wt1: [128][320]
        int c = id / K1, k = id - c * K1;
        Wt1[id] = f2bf(W1[(size_t)k * HID + c]);
    }
    if (id < HID * HID) {                    // Wt2: [128][128]
        int c = id >> 7, k = id & 127;
        Wt2[id] = f2bf(W2[(size_t)k * HID + c]);
    }
}

// ---------- CSR build ----------

__global__ __launch_bounds__(256) void hist_kernel(
    const int* __restrict__ col, int* __restrict__ deg, int E)
{
    int e = blockIdx.x * 256 + threadIdx.x;
    if (e < E) atomicAdd(&deg[col[e]], 1);
}

// partial sums: each block covers 1024 elements of deg
__global__ __launch_bounds__(256) void scan_partial(
    const int* __restrict__ deg, int* __restrict__ blockSums, int N)
{
    __shared__ int sdata[256];
    int base = blockIdx.x * 1024;
    int tid  = threadIdx.x;
    int s = 0;
    #pragma unroll
    for (int j = 0; j < 4; ++j) {
        int i = base + tid * 4 + j;
        if (i < N) s += deg[i];
    }
    sdata[tid] = s;
    __syncthreads();
    for (int off = 128; off > 0; off >>= 1) {
        if (tid < off) sdata[tid] += sdata[tid + off];
        __syncthreads();
    }
    if (tid == 0) blockSums[blockIdx.x] = sdata[0];
}

// final: computes its own blockSums prefix (separate scan kernel folded in)
__global__ __launch_bounds__(256) void scan_final(
    const int* __restrict__ deg, const int* __restrict__ blockSums,
    int* __restrict__ offsets, int* __restrict__ cur, int N, int E)
{
    __shared__ int sdata[256];
    __shared__ int rdata[256];
    int tid = threadIdx.x;

    // prefix of blockSums[0..blockIdx-1] via strided reduce (NB <= 1024)
    int part = 0;
    for (int i = tid; i < (int)blockIdx.x; i += 256) part += blockSums[i];
    rdata[tid] = part;
    __syncthreads();
    for (int off = 128; off > 0; off >>= 1) {
        if (tid < off) rdata[tid] += rdata[tid + off];
        __syncthreads();
    }
    const int blockPrefix = rdata[0];

    int base = blockIdx.x * 1024;
    int loc[4];
    int s = 0;
    #pragma unroll
    for (int j = 0; j < 4; ++j) {
        int i = base + tid * 4 + j;
        loc[j] = (i < N) ? deg[i] : 0;
        s += loc[j];
    }
    int mine = s;
    sdata[tid] = s;
    __syncthreads();
    for (int off = 1; off < 256; off <<= 1) {
        int t = (tid >= off) ? sdata[tid - off] : 0;
        __syncthreads();
        sdata[tid] += t;
        __syncthreads();
    }
    int prefix = blockPrefix + sdata[tid] - mine;
    #pragma unroll
    for (int j = 0; j < 4; ++j) {
        int i = base + tid * 4 + j;
        if (i < N) { offsets[i] = prefix; cur[i] = prefix; prefix += loc[j]; }
    }
    if (blockIdx.x == 0 && tid == 0) offsets[N] = E;
}

__global__ __launch_bounds__(256) void fill_kernel(
    const int* __restrict__ col, int* __restrict__ cur,
    int* __restrict__ eidx, int E)
{
    int e = blockIdx.x * 256 + threadIdx.x;
    if (e < E) {
        int p = atomicAdd(&cur[col[e]], 1);
        eidx[p] = e;
    }
}

// ---------- fused gather + 2-layer MLP via bf16 MFMA (R9 structure) ----------
// block = 512 threads = 8 waves; wave w owns output cols [16w, 16w+15];
// ROWS = 32 nodes/block, two 16-row tiles per wave share its in-reg W frags.
// Gather: eidx slice + offsets slice in LDS, ILP-4 edge walks, NT loads on
// edge_attr only (read-once). No sched_barrier (let compiler hoist W loads
// into the gather latency shadow — R10 showed pinning them costs ~8 us).
#define ROWS 32
#define LDA_E 328
#define LDH_E 136
#define ECAP 1280

__global__ __launch_bounds__(512, 4) void mlp_mfma(
    const float* __restrict__ x,
    const float* __restrict__ edge_attr,
    const int*   __restrict__ offsets,
    const int*   __restrict__ eidx,
    const float* __restrict__ u,
    const int*   __restrict__ batch,
    const unsigned short* __restrict__ Wt1,
    const unsigned short* __restrict__ Wt2,
    const float* __restrict__ b1, const float* __restrict__ b2,
    float* __restrict__ out, int N)
{
    __shared__ __align__(16) unsigned short A[ROWS * LDA_E];
    __shared__ __align__(16) unsigned short H[ROWS * LDH_E];
    __shared__ int Eidx[ECAP];
    __shared__ int Soff[ROWS + 1];
    const int tid  = threadIdx.x;
    const int n0   = blockIdx.x * ROWS;
    const int lane = tid & 63;
    const int wave = tid >> 6;       // 0..7 = which 16-col slice
    const int l15  = lane & 15;
    const int lhi  = lane >> 4;      // 0..3
    const int wcol = wave * 16 + l15;

    // ---- stage offsets slice (33 ints) and this tile's eidx slice into LDS
    const int nEnd   = (n0 + ROWS < N) ? n0 + ROWS : N;
    if (tid <= ROWS) {
        int idx = n0 + tid;
        Soff[tid] = offsets[(idx < nEnd) ? idx : nEnd];
    }
    const int s_base = offsets[n0];
    const int s_end  = offsets[nEnd];
    const int cnt    = (s_end - s_base < ECAP) ? s_end - s_base : ECAP;
    for (int i = tid; i < cnt; i += 512) Eidx[i] = eidx[s_base + i];

    // ---- stage x (32 float4 segs/row) and u (16 segs/row): 32*48 = 1536 tasks
    #pragma unroll
    for (int it = 0; it < 3; ++it) {
        int t   = tid + it * 512;
        int row = t / 48;
        int s   = t - row * 48;
        int n   = n0 + row;
        unsigned short* Arow = &A[row * LDA_E];
        float4 v = make_float4(0.f, 0.f, 0.f, 0.f);
        int colbase;
        if (s < 32) {                                // x: cols 0..127
            if (n < N) v = ((const float4*)(x + (size_t)n * V_IN))[s];
            colbase = s * 4;
        } else {                                     // u: cols 256..319
            if (n < N) {
                int b = batch[n];
                v = ((const float4*)(u + (size_t)b * U_IN))[s - 32];
            }
            colbase = V_IN + HID + (s - 32) * 4;
        }
        uint2 o; o.x = f2bf2(v.x, v.y); o.y = f2bf2(v.z, v.w);
        *(uint2*)&Arow[colbase] = o;
    }
    __syncthreads();   // Eidx, Soff visible

    // ---- gather agg into A cols 128..255: 32 rows x 32 chunks, ILP-4,
    //      indices from LDS, rows via nontemporal loads
    #pragma unroll
    for (int it = 0; it < 2; ++it) {
        int t   = tid + it * 512;
        int row = t >> 5;
        int c   = t & 31;
        int n   = n0 + row;
        f32x4 a0 = {0.f, 0.f, 0.f, 0.f};
        f32x4 a1 = {0.f, 0.f, 0.f, 0.f};
        f32x4 a2 = {0.f, 0.f, 0.f, 0.f};
        f32x4 a3 = {0.f, 0.f, 0.f, 0.f};
        if (n < N) {
            int ls = Soff[row]     - s_base;
            int le = Soff[row + 1] - s_base;
            int j = ls;
            for (; j + 3 < le; j += 4) {
                int e0, e1, e2, e3;
                if (j + 3 < ECAP) {
                    e0 = Eidx[j];     e1 = Eidx[j + 1];
                    e2 = Eidx[j + 2]; e3 = Eidx[j + 3];
                } else {
                    e0 = eidx[s_base + j];     e1 = eidx[s_base + j + 1];
                    e2 = eidx[s_base + j + 2]; e3 = eidx[s_base + j + 3];
                }
                f32x4 v0 = __builtin_nontemporal_load((const f32x4*)(edge_attr + (size_t)e0 * HID) + c);
                f32x4 v1 = __builtin_nontemporal_load((const f32x4*)(edge_attr + (size_t)e1 * HID) + c);
                f32x4 v2 = __builtin_nontemporal_load((const f32x4*)(edge_attr + (size_t)e2 * HID) + c);
                f32x4 v3 = __builtin_nontemporal_load((const f32x4*)(edge_attr + (size_t)e3 * HID) + c);
                a0 += v0; a1 += v1; a2 += v2; a3 += v3;
            }
            for (; j < le; ++j) {
                int e0 = (j < ECAP) ? Eidx[j] : eidx[s_base + j];
                a0 += __builtin_nontemporal_load((const f32x4*)(edge_attr + (size_t)e0 * HID) + c);
            }
        }
        f32x4 asum = (a0 + a1) + (a2 + a3);
        uint2 o;
        o.x = f2bf2(asum[0], asum[1]);
        o.y = f2bf2(asum[2], asum[3]);
        *(uint2*)&A[row * LDA_E + V_IN + c * 4] = o;
    }

    // ---- W fragments into registers (B-operand: col=l15, k contiguous)
    bf16x8 w1f[10], w2f[4];
    #pragma unroll
    for (int ks = 0; ks < 10; ++ks)
        w1f[ks] = *(const bf16x8*)(Wt1 + (size_t)wcol * K1 + ks * 32 + lhi * 8);
    #pragma unroll
    for (int ks = 0; ks < 4; ++ks)
        w2f[ks] = *(const bf16x8*)(Wt2 + (size_t)wcol * HID + ks * 32 + lhi * 8);
    const float b1v = b1[wcol];
    const float b2v = b2[wcol];

    __syncthreads();

    // ---- layer 1: two 16-row tiles share w1f
    f32x4 acc[2] = {{0.f, 0.f, 0.f, 0.f}, {0.f, 0.f, 0.f, 0.f}};
    #pragma unroll
    for (int ks = 0; ks < 10; ++ks) {
        #pragma unroll
        for (int h = 0; h < 2; ++h) {
            bf16x8 af = *(const bf16x8*)&A[(h * 16 + l15) * LDA_E + ks * 32 + lhi * 8];
            acc[h] = __builtin_amdgcn_mfma_f32_16x16x32_bf16(af, w1f[ks], acc[h], 0, 0, 0);
        }
    }
    // bias + relu -> H (D layout: row = lhi*4+r, col = l15 in wave's slice)
    #pragma unroll
    for (int h = 0; h < 2; ++h)
        #pragma unroll
        for (int r = 0; r < 4; ++r) {
            float hv = fmaxf(acc[h][r] + b1v, 0.f);
            H[(h * 16 + lhi * 4 + r) * LDH_E + wcol] = f2bf(hv);
        }
    __syncthreads();

    // ---- layer 2: two 16-row tiles share w2f
    f32x4 acc2[2] = {{0.f, 0.f, 0.f, 0.f}, {0.f, 0.f, 0.f, 0.f}};
    #pragma unroll
    for (int ks = 0; ks < 4; ++ks) {
        #pragma unroll
        for (int h = 0; h < 2; ++h) {
            bf16x8 hf = *(const bf16x8*)&H[(h * 16 + l15) * LDH_E + ks * 32 + lhi * 8];
            acc2[h] = __builtin_amdgcn_mfma_f32_16x16x32_bf16(hf, w2f[ks], acc2[h], 0, 0, 0);
        }
    }
    #pragma unroll
    for (int h = 0; h < 2; ++h)
        #pragma unroll
        for (int r = 0; r < 4; ++r) {
            int n = n0 + h * 16 + lhi * 4 + r;
            if (n < N) out[(size_t)n * HID + wcol] = acc2[h][r] + b2v;
        }
}

extern "C" void kernel_launch(void* const* d_in, const int* in_sizes, int n_in,
                              void* d_out, int out_size, void* d_ws, size_t ws_size,
                              hipStream_t stream) {
    const float* x          = (const float*)d_in[0];
    const int*   edge_index = (const int*)  d_in[1];
    const float* edge_attr  = (const float*)d_in[2];
    const float* u          = (const float*)d_in[3];
    const int*   batch      = (const int*)  d_in[4];
    const float* W1         = (const float*)d_in[5];
    const float* b1         = (const float*)d_in[6];
    const float* W2         = (const float*)d_in[7];
    const float* b2         = (const float*)d_in[8];
    float* out = (float*)d_out;

    const int N = in_sizes[0] / V_IN;
    const int E = in_sizes[1] / 2;
    const int* col = edge_index + E;   // row 1 = destination

    // ws layout
    unsigned short* Wt1  = (unsigned short*)d_ws;        // 320*128 bf16
    unsigned short* Wt2  = Wt1 + (size_t)K1 * HID;       // 128*128 bf16
    int* deg       = (int*)(Wt2 + (size_t)HID * HID);
    int* cur       = deg + N;
    int* offsets   = cur + N;
    int* blockSums = offsets + N + 1;
    int* eidx      = blockSums + 2048;

    const int NB = (N + 1023) / 1024;
    const int ZP = ((N > HID * K1 ? N : HID * K1) + 255) / 256;

    zero_prep   <<<ZP, 256, 0, stream>>>(W1, W2, Wt1, Wt2, deg, N);
    hist_kernel <<<(E + 255) / 256, 256, 0, stream>>>(col, deg, E);
    scan_partial<<<NB, 256, 0, stream>>>(deg, blockSums, N);
    scan_final  <<<NB, 256, 0, stream>>>(deg, blockSums, offsets, cur, N, E);
    fill_kernel <<<(E + 255) / 256, 256, 0, stream>>>(col, cur, eidx, E);

    mlp_mfma<<<(N + ROWS - 1) / ROWS, 512, 0, stream>>>(
        x, edge_attr, offsets, eidx, u, batch, Wt1, Wt2, b1, b2, out, N);
}